// Round 5
// baseline (640.828 us; speedup 1.0000x reference)
//
#include <hip/hip_runtime.h>

// x: (B=16, C=256, W=64, P=128) fp32 ; codebooks: (NS=4, K=256, SC=64) fp32
#define NSQ 4
#define KCB 256
#define SCH 64
#define NVEC (16*64*128)              // 131072 vectors per subspace

// ---------------------------------------------------------------------------
// Pass 0: codebook norms, bit-identical fmaf order to pass1's epilogue use.
// Result parked in d_out[0..1023] (pass2 later overwrites all of d_out).
// ---------------------------------------------------------------------------
__global__ void pq_norms(const float* __restrict__ cb, float* __restrict__ cn)
{
    const int s = blockIdx.x, k = threadIdx.x;
    const float* row = cb + (size_t)(s * KCB + k) * SCH;
    float n = 0.f;
#pragma unroll
    for (int j4 = 0; j4 < 16; ++j4) {
        float4 v = *(const float4*)(row + j4 * 4);
        n = fmaf(v.x, v.x, n); n = fmaf(v.y, v.y, n);
        n = fmaf(v.z, v.z, n); n = fmaf(v.w, v.w, n);
    }
    cn[s * KCB + k] = n;
}

// ---------------------------------------------------------------------------
// Pass 1: argmin_k ( ||cb[s,k]||^2 - 2 * x_n . cb[s,k] ), k = 0..255.
// Chunked codebook staging: cbt[16][256] = 16 KiB, 4 chunks of j per tile,
// acc[4][16] persists across chunks (fmaf order identical to prior rounds).
// 256 threads (tk 0..15 x tn 0..15), n-tile 64, launch_bounds(256,4):
// VGPR cap 128 (body needs ~120), 4 waves/SIMD -> 16 waves/CU, 4 blocks/CU.
// ---------------------------------------------------------------------------
__global__ __launch_bounds__(256, 4) void pq_pass1(const float* __restrict__ x,
                                                   const float* __restrict__ cb,
                                                   const float* __restrict__ cnorm,
                                                   int* __restrict__ idx_out)
{
    __shared__ float cbt[16][256];          // 16 KiB
    const int tid  = threadIdx.x;
    const int s    = blockIdx.x >> 11;      // 2048 n-tiles per subspace
    const int blkn = blockIdx.x & 2047;
    const int tk   = tid & 15;
    const int tn   = tid >> 4;              // 0..15
    const int swz  = ((tk ^ (tk >> 2)) & 3) << 2;

    const int n_base = blkn * 64;
    const int b   = n_base >> 13;
    const int w   = (n_base >> 7) & 63;
    const int p0  = n_base & 127;           // 0 or 64

    // staging role: this thread stages codebook row k = tid (swizzled column)
    const int k    = tid;
    const int tks  = k >> 4;
    const int szs  = ((tks ^ (tks >> 2)) & 3) << 2;
    const int col  = (k & ~15) | ((k & 15) ^ szs);
    const float* cbrow = cb + (size_t)(s * KCB + k) * SCH;

    const int cb0 = (tk << 4) | (0  ^ swz);
    const int cb1 = (tk << 4) | (4  ^ swz);
    const int cb2 = (tk << 4) | (8  ^ swz);
    const int cb3 = (tk << 4) | (12 ^ swz);
    const float* cnp = cnorm + s * KCB + (tk << 4);

    // x fragment pointer (j stride = 8192 floats); prime j=0 prefetch
    const float* xp = x + ((size_t)((b * 256 + s * 64) * 64 + w)) * 128 + p0 + 4 * tn;
    float4 xv = *(const float4*)xp;

    float acc[4][16];
#pragma unroll
    for (int nn = 0; nn < 4; ++nn)
#pragma unroll
        for (int kk = 0; kk < 16; ++kk) acc[nn][kk] = 0.f;

    for (int ch = 0; ch < 4; ++ch) {
        __syncthreads();                    // prior chunk's reads complete
        {
            const float* rp = cbrow + ch * 16;
            float4 v0 = *(const float4*)(rp + 0);
            float4 v1 = *(const float4*)(rp + 4);
            float4 v2 = *(const float4*)(rp + 8);
            float4 v3 = *(const float4*)(rp + 12);
            cbt[ 0][col] = v0.x; cbt[ 1][col] = v0.y; cbt[ 2][col] = v0.z; cbt[ 3][col] = v0.w;
            cbt[ 4][col] = v1.x; cbt[ 5][col] = v1.y; cbt[ 6][col] = v1.z; cbt[ 7][col] = v1.w;
            cbt[ 8][col] = v2.x; cbt[ 9][col] = v2.y; cbt[10][col] = v2.z; cbt[11][col] = v2.w;
            cbt[12][col] = v3.x; cbt[13][col] = v3.y; cbt[14][col] = v3.z; cbt[15][col] = v3.w;
        }
        __syncthreads();                    // stage visible

#pragma unroll
        for (int jj = 0; jj < 16; ++jj) {
            const int j  = ch * 16 + jj;
            const int jn = (j < 63) ? (j + 1) : 63;        // clamp (scalar)
            float4 xn = *(const float4*)(xp + (size_t)jn * 8192);
            float c[16];
            {
                float4 t0 = *(const float4*)&cbt[jj][cb0];
                float4 t1 = *(const float4*)&cbt[jj][cb1];
                float4 t2 = *(const float4*)&cbt[jj][cb2];
                float4 t3 = *(const float4*)&cbt[jj][cb3];
                c[0]=t0.x; c[1]=t0.y; c[2]=t0.z; c[3]=t0.w;
                c[4]=t1.x; c[5]=t1.y; c[6]=t1.z; c[7]=t1.w;
                c[8]=t2.x; c[9]=t2.y; c[10]=t2.z; c[11]=t2.w;
                c[12]=t3.x; c[13]=t3.y; c[14]=t3.z; c[15]=t3.w;
            }
#pragma unroll
            for (int kk = 0; kk < 16; ++kk) {
                acc[0][kk] = fmaf(xv.x, c[kk], acc[0][kk]);
                acc[1][kk] = fmaf(xv.y, c[kk], acc[1][kk]);
                acc[2][kk] = fmaf(xv.z, c[kk], acc[2][kk]);
                acc[3][kk] = fmaf(xv.w, c[kk], acc[3][kk]);
            }
            xv = xn;
        }
    }

    // per-thread argmin over its 16 k (first-index tie-break)
    float best[4] = {3.4e38f, 3.4e38f, 3.4e38f, 3.4e38f};
    int   bidx[4] = {0, 0, 0, 0};
#pragma unroll
    for (int kk = 0; kk < 16; ++kk) {
        const float cn = cnp[kk];
        const int kx = (tk << 4) + kk;
#pragma unroll
        for (int nn = 0; nn < 4; ++nn) {
            float d = fmaf(-2.f, acc[nn][kk], cn);
            bool better = (d < best[nn]);
            best[nn] = better ? d : best[nn];
            bidx[nn] = better ? kx : bidx[nn];
        }
    }
    // reduce across the 16 tk lanes (same wave)
#pragma unroll
    for (int m = 8; m; m >>= 1) {
#pragma unroll
        for (int nn = 0; nn < 4; ++nn) {
            float ob = __shfl_xor(best[nn], m, 64);
            int   oi = __shfl_xor(bidx[nn], m, 64);
            bool take = (ob < best[nn]) || (ob == best[nn] && oi < bidx[nn]);
            best[nn] = take ? ob : best[nn];
            bidx[nn] = take ? oi : bidx[nn];
        }
    }
    if (tk == 0) {
        int4 r; r.x = bidx[0]; r.y = bidx[1]; r.z = bidx[2]; r.w = bidx[3];
        *(int4*)(idx_out + (size_t)s * NVEC + n_base + 4 * tn) = r;
    }
}

// ---------------------------------------------------------------------------
// Pass 2 (byte-identical to round 3; counters needed before changing it):
// out[b,c,w,p] = cb[s, idx[s, b*8192 + p*64 + w], c&63],  s = c>>6
// ---------------------------------------------------------------------------
__global__ __launch_bounds__(256) void pq_pass2(const float* __restrict__ cb,
                                                const int* __restrict__ idx,
                                                float* __restrict__ out)
{
    __shared__ int   L[64][65];        // 16.6 KiB
    __shared__ float cbs[256][9];      // 9.2 KiB
    const int tid = threadIdx.x;
    const int bid = blockIdx.x;
    const int jq  = bid & 7;           // j group (8 channels)
    const int ph  = (bid >> 3) & 1;    // p half
    const int s   = (bid >> 4) & 3;
    const int b   = bid >> 6;
    const int p0  = ph * 64;
    const int j0  = jq * 8;

    // stage idx tile (coalesced): g = (p-p0)*64 + w
    const int* ip = idx + (size_t)s * NVEC + b * 8192 + p0 * 64;
#pragma unroll
    for (int it = 0; it < 16; ++it) {
        int g = it * 256 + tid;
        L[g & 63][g >> 6] = ip[g];
    }
    // stage 8-wide codebook slice: 256 k x 8 jj
    const float* cp = cb + (size_t)s * (KCB * SCH) + j0;
#pragma unroll
    for (int it = 0; it < 2; ++it) {
        int t = it * 256 + tid;        // 512 float4 chunks
        int k = t >> 1, jj4 = (t & 1) * 4;
        float4 v = *(const float4*)(cp + (size_t)k * SCH + jj4);
        cbs[k][jj4 + 0] = v.x; cbs[k][jj4 + 1] = v.y;
        cbs[k][jj4 + 2] = v.z; cbs[k][jj4 + 3] = v.w;
    }
    __syncthreads();

    // preload this thread's 16 k-values (4 float4-positions), reuse for 8 cc
    int kv[4][4];
#pragma unroll
    for (int q = 0; q < 4; ++q) {
        int ch = q * 256 + tid;        // w = ch>>4 (0..63), pp = (ch&15)*4
        int w  = ch >> 4, pp = (ch & 15) * 4;
#pragma unroll
        for (int e = 0; e < 4; ++e) kv[q][e] = L[w][pp + e];
    }

#pragma unroll
    for (int cc = 0; cc < 8; ++cc) {
        const int c = s * 64 + j0 + cc;
        float* op = out + ((size_t)(b * 256 + c) * 64) * 128 + p0;
#pragma unroll
        for (int q = 0; q < 4; ++q) {
            int ch = q * 256 + tid;
            int w  = ch >> 4, pp = (ch & 15) * 4;
            float4 v;
            v.x = cbs[kv[q][0]][cc];
            v.y = cbs[kv[q][1]][cc];
            v.z = cbs[kv[q][2]][cc];
            v.w = cbs[kv[q][3]][cc];
            *(float4*)(op + (size_t)w * 128 + pp) = v;
        }
    }
}

extern "C" void kernel_launch(void* const* d_in, const int* in_sizes, int n_in,
                              void* d_out, int out_size, void* d_ws, size_t ws_size,
                              hipStream_t stream) {
    (void)in_sizes; (void)n_in; (void)out_size; (void)ws_size;
    const float* x   = (const float*)d_in[0];
    const float* cbk = (const float*)d_in[1];
    float*       out = (float*)d_out;
    int*         idx = (int*)d_ws;            // 2 MiB scratch
    float*       cnrm = (float*)d_out;        // parked in d_out; pass2 overwrites

    pq_norms<<<NSQ, KCB, 0, stream>>>(cbk, cnrm);
    pq_pass1<<<NSQ * 2048, 256, 0, stream>>>(x, cbk, cnrm, idx);
    pq_pass2<<<16 * NSQ * 2 * 8, 256, 0, stream>>>(cbk, idx, out);
}